// Round 1
// baseline (326.084 us; speedup 1.0000x reference)
//
#include <hip/hip_runtime.h>

typedef _Float16 f16;
typedef _Float16 f16x2 __attribute__((ext_vector_type(2)));
typedef _Float16 f16x8 __attribute__((ext_vector_type(8)));
typedef float f32x4 __attribute__((ext_vector_type(4)));

#define B_   4
#define C_   256
#define N_   4096
#define OUT_ 256

// ---------------------------------------------------------------------------
// Kernel A: transpose+convert x [B,C,N] f32 -> xt [B,N,C] f16, W -> Wt[o][c] f16,
// and zero the 512-float stats accumulator (sum, sumsq per channel).
// ---------------------------------------------------------------------------
__global__ __launch_bounds__(256) void k_prep(const float* __restrict__ x,
                                              const float* __restrict__ W,
                                              f16* __restrict__ xt,
                                              f16* __restrict__ Wt,
                                              float* __restrict__ stats) {
    int bid = blockIdx.x;
    int t = threadIdx.x;
    if (bid < 1024) {
        int b  = bid >> 8;
        int ct = (bid >> 6) & 3;
        int nt = bid & 63;
        int c0 = ct * 64, n0 = nt * 64;
        __shared__ float tile[64][65];
        int nl = t & 63;
        int r0 = t >> 6;
        #pragma unroll
        for (int i = 0; i < 16; ++i) {
            int cl = i * 4 + r0;
            tile[cl][nl] = x[((b * C_ + c0 + cl) * N_) + n0 + nl];
        }
        __syncthreads();
        #pragma unroll
        for (int i = 0; i < 16; ++i) {
            int nl2 = i * 4 + r0;
            int cl2 = nl;
            xt[((b * N_ + n0 + nl2) * C_) + c0 + cl2] = (f16)tile[cl2][nl2];
        }
    } else {
        int wb = bid - 1024;
        #pragma unroll
        for (int i = 0; i < 4; ++i) {
            int idx = wb * 1024 + i * 256 + t;
            int c = idx >> 8, o = idx & 255;
            Wt[o * C_ + c] = (f16)W[idx];
        }
        if (wb < 2) stats[wb * 256 + t] = 0.f;
    }
}

// ---------------------------------------------------------------------------
// Kernel B: support^T[b][o][m] = sum_c xt[b][m][c] * W[c][o]   (f16 out)
// XCD-clustered bid remap: each XCD pair works on one batch (2.1 MB < 4 MB L2).
// ---------------------------------------------------------------------------
__global__ __launch_bounds__(256) void k_support(const f16* __restrict__ xt,
                                                 const f16* __restrict__ Wt,
                                                 f16* __restrict__ supT) {
    int bid0 = blockIdx.x;
    int bid = (bid0 & 7) * 128 + (bid0 >> 3);   // bijective, clusters b per XCD
    int b  = bid >> 8;
    int ot = (bid >> 6) & 3;
    int mt = bid & 63;
    int o0 = ot * 64, m0 = mt * 64;
    __shared__ __align__(16) f16 Ws[64][264];
    __shared__ __align__(16) f16 Xs[64][264];
    int t = threadIdx.x;
    int wave = t >> 6, lane = t & 63, q = lane >> 4, l15 = lane & 15;
    #pragma unroll
    for (int p = 0; p < 8; ++p) {
        int idx = p * 256 + t;
        int row = idx >> 5, ch = (idx & 31) * 8;
        *(uint4*)&Ws[row][ch] = *(const uint4*)&Wt[(o0 + row) * C_ + ch];
        *(uint4*)&Xs[row][ch] = *(const uint4*)&xt[((b * N_) + m0 + row) * C_ + ch];
    }
    __syncthreads();
    f32x4 acc[4] = {};
    #pragma unroll
    for (int kk = 0; kk < 8; ++kk) {
        f16x8 a = *(f16x8*)&Ws[16 * wave + l15][kk * 32 + q * 8];
        #pragma unroll
        for (int ct = 0; ct < 4; ++ct) {
            f16x8 bb = *(f16x8*)&Xs[16 * ct + l15][kk * 32 + q * 8];
            acc[ct] = __builtin_amdgcn_mfma_f32_16x16x32_f16(a, bb, acc[ct], 0, 0, 0);
        }
    }
    #pragma unroll
    for (int ct = 0; ct < 4; ++ct)
        #pragma unroll
        for (int r = 0; r < 4; ++r) {
            int og = o0 + 16 * wave + q * 4 + r;
            int mg = m0 + 16 * ct + l15;
            supT[((b * OUT_ + og) * N_) + mg] = (f16)acc[ct][r];
        }
}

// ---------------------------------------------------------------------------
// Kernel C: split-K flash. 512 blocks: (half h, batch b, n-tile nb), remapped
// so each XCD owns exactly one (h,b) pair (K-half 1MB + supT 2MB fits L2).
// Structure per iter (2 light barriers, loads stay in flight across B):
//   write Ks from kreg -> syncA -> prefetch next K->kreg -> QK^T (setprio)
//   -> prefetch V frags (global) -> softmax -> [lgkmcnt(0); s_barrier] ->
//   rescale -> PV with global-V fragments (setprio)
// V is NOT staged in LDS (L2-resident; staging was pure overhead).
// LDS: 43.3 KB (was 80.4).
// ---------------------------------------------------------------------------
__global__ __launch_bounds__(256, 2) void k_flash(const f16* __restrict__ xt,
                                                  const f16* __restrict__ supT,
                                                  f16* __restrict__ Op,
                                                  float* __restrict__ Ml) {
    int bid0 = blockIdx.x;
    int wg = (bid0 & 7) * 64 + (bid0 >> 3);   // XCD x owns wg in [64x, 64x+64)
    int h  = wg >> 8;
    int b  = (wg >> 6) & 3;
    int n0 = (wg & 63) * 64;

    __shared__ __align__(16) f16 Ks[64][264];   // 33792 B
    __shared__ __align__(16) f16 Ps[64][72];    //  9216 B
    __shared__ float Al[64];                    //   256 B  -> 43264 B total

    int t = threadIdx.x;
    int wave = t >> 6, lane = t & 63, q = lane >> 4, l15 = lane & 15;

    // Q fragments in registers
    const f16* qbase = xt + ((size_t)(b * N_) + n0 + 16 * wave + l15) * C_;
    f16x8 qf[8];
    #pragma unroll
    for (int kk = 0; kk < 8; ++kk)
        qf[kk] = *(const f16x8*)&qbase[kk * 32 + q * 8];

    f32x4 oacc[4][4] = {};
    float m_run[4], l_run[4];
    #pragma unroll
    for (int r = 0; r < 4; ++r) { m_run[r] = -1e30f; l_run[r] = 0.f; }

    const f16* kbase = xt + (size_t)b * N_ * C_;
    int srow = t >> 5;          // staging row-within-8, col: 8 rows per p
    int sch  = (t & 31) * 8;

    // prologue: prefetch K tile 0 into registers
    uint4 kr[8];
    #pragma unroll
    for (int p = 0; p < 8; ++p)
        kr[p] = *(const uint4*)&kbase[(h * 2048 + p * 8 + srow) * C_ + sch];

    for (int it = 0; it < 32; ++it) {
        int m0 = h * 2048 + it * 64;

        // commit staged K tile to LDS (waits kr's vmcnt by use)
        #pragma unroll
        for (int p = 0; p < 8; ++p)
            *(uint4*)&Ks[p * 8 + srow][sch] = kr[p];
        __syncthreads();   // A: nothing in flight here by construction

        // async prefetch next K tile (in flight across barrier B, consumed next iter)
        if (it < 31) {
            #pragma unroll
            for (int p = 0; p < 8; ++p)
                kr[p] = *(const uint4*)&kbase[(m0 + 64 + p * 8 + srow) * C_ + sch];
        }

        // S = Q K^T (64x64, K=256); wave owns rows 16*wave..+15
        f32x4 sacc[4] = {};
        __builtin_amdgcn_s_setprio(1);
        #pragma unroll
        for (int kk = 0; kk < 8; ++kk) {
            #pragma unroll
            for (int ct = 0; ct < 4; ++ct) {
                f16x8 bb = *(f16x8*)&Ks[16 * ct + l15][kk * 32 + q * 8];
                sacc[ct] = __builtin_amdgcn_mfma_f32_16x16x32_f16(qf[kk], bb, sacc[ct], 0, 0, 0);
            }
        }
        __builtin_amdgcn_s_setprio(0);

        // prefetch V fragments for THIS iter straight from global (L2-resident);
        // latency hides under softmax + barrier + rescale
        f16x8 vf[2][4];
        const f16* vb = supT + ((size_t)(b * OUT_) + 64 * wave + l15) * N_ + m0 + q * 8;
        #pragma unroll
        for (int ks = 0; ks < 2; ++ks)
            #pragma unroll
            for (int ot = 0; ot < 4; ++ot)
                vf[ks][ot] = *(const f16x8*)&vb[(size_t)(16 * ot) * N_ + ks * 32];

        // online softmax on own rows; publish P (f16) and alpha
        float alpha[4];
        #pragma unroll
        for (int r = 0; r < 4; ++r) {
            float mx = fmaxf(fmaxf(sacc[0][r], sacc[1][r]), fmaxf(sacc[2][r], sacc[3][r]));
            mx = fmaxf(mx, __shfl_xor(mx, 1));
            mx = fmaxf(mx, __shfl_xor(mx, 2));
            mx = fmaxf(mx, __shfl_xor(mx, 4));
            mx = fmaxf(mx, __shfl_xor(mx, 8));
            float mnew = fmaxf(m_run[r], mx);
            alpha[r] = __expf(m_run[r] - mnew);
            m_run[r] = mnew;
            float p0 = __expf(sacc[0][r] - mnew);
            float p1 = __expf(sacc[1][r] - mnew);
            float p2 = __expf(sacc[2][r] - mnew);
            float p3 = __expf(sacc[3][r] - mnew);
            float sum = p0 + p1 + p2 + p3;
            sum += __shfl_xor(sum, 1);
            sum += __shfl_xor(sum, 2);
            sum += __shfl_xor(sum, 4);
            sum += __shfl_xor(sum, 8);
            l_run[r] = l_run[r] * alpha[r] + sum;
            int row = 16 * wave + q * 4 + r;
            Ps[row][0 * 16 + l15] = (f16)p0;
            Ps[row][1 * 16 + l15] = (f16)p1;
            Ps[row][2 * 16 + l15] = (f16)p2;
            Ps[row][3 * 16 + l15] = (f16)p3;
            if (l15 == 0) Al[row] = alpha[r];
        }

        // B: light barrier — drain LDS writes only, keep kr/vf global loads in flight
        asm volatile("s_waitcnt lgkmcnt(0)" ::: "memory");
        __builtin_amdgcn_s_barrier();
        __builtin_amdgcn_sched_barrier(0);

        // rescale O by alpha (broadcast via LDS), then O += P V
        float4 av[4];
        #pragma unroll
        for (int nt = 0; nt < 4; ++nt)
            av[nt] = *(const float4*)&Al[16 * nt + 4 * q];
        #pragma unroll
        for (int nt = 0; nt < 4; ++nt)
            #pragma unroll
            for (int ot = 0; ot < 4; ++ot)
                #pragma unroll
                for (int r = 0; r < 4; ++r)
                    oacc[nt][ot][r] *= ((const float*)&av[nt])[r];

        __builtin_amdgcn_s_setprio(1);
        #pragma unroll
        for (int ks = 0; ks < 2; ++ks) {
            f16x8 af[4];
            #pragma unroll
            for (int nt = 0; nt < 4; ++nt)
                af[nt] = *(f16x8*)&Ps[16 * nt + l15][ks * 32 + q * 8];
            #pragma unroll
            for (int nt = 0; nt < 4; ++nt)
                #pragma unroll
                for (int ot = 0; ot < 4; ++ot)
                    oacc[nt][ot] = __builtin_amdgcn_mfma_f32_16x16x32_f16(af[nt], vf[ks][ot], oacc[nt][ot], 0, 0, 0);
        }
        __builtin_amdgcn_s_setprio(0);
        // no trailing barrier: next iter's Ks write is safe (all Ks reads drained
        // at B), and next Ps/Al writes happen after the next A.
    }

    __syncthreads();   // protect Al reuse against stragglers in last PV/rescale
    if (l15 == 0) {
        #pragma unroll
        for (int r = 0; r < 4; ++r)
            Al[16 * wave + q * 4 + r] = 1.0f / l_run[r];
    }
    __syncthreads();
    float4 lv[4];
    #pragma unroll
    for (int nt = 0; nt < 4; ++nt)
        lv[nt] = *(const float4*)&Al[16 * nt + 4 * q];

    f16* Obase = Op + (size_t)wg * (64 * 256);
    #pragma unroll
    for (int nt = 0; nt < 4; ++nt)
        #pragma unroll
        for (int ot = 0; ot < 4; ++ot)
            #pragma unroll
            for (int r = 0; r < 4; ++r) {
                int n = 16 * nt + q * 4 + r;
                int o = 64 * wave + 16 * ot + l15;
                Obase[n * 256 + o] = (f16)(oacc[nt][ot][r] * ((const float*)&lv[nt])[r]);
            }
    float* Mlb = Ml + (size_t)wg * 128;
    if (l15 == 0) {
        #pragma unroll
        for (int r = 0; r < 4; ++r) {
            Mlb[16 * wave + q * 4 + r] = m_run[r];
            Mlb[64 + 16 * wave + q * 4 + r] = l_run[r];
        }
    }
}

// ---------------------------------------------------------------------------
// Kernel C2: merge the two split-K halves + LeakyReLU + fused BN partial sums
// + coalesced transpose store via LDS. grid 256 = (b, nb).
// Thread (p2 = 2*(t&127), nh = (t>>7)*32) owns channels p2,p2+1 over 32 rows.
// ---------------------------------------------------------------------------
__global__ __launch_bounds__(256) void k_merge(const f16* __restrict__ Op,
                                               const float* __restrict__ Ml,
                                               float* __restrict__ out,
                                               float* __restrict__ stats) {
    int bid = blockIdx.x;
    int b  = bid >> 6;
    int n0 = (bid & 63) * 64;
    int t = threadIdx.x;
    const f16* O1 = Op + (size_t)bid * (64 * 256);
    const f16* O2 = Op + (size_t)(bid + 256) * (64 * 256);
    const float* Ml1 = Ml + (size_t)bid * 128;
    const float* Ml2 = Ml + (size_t)(bid + 256) * 128;
    __shared__ float c1s[64], c2s[64];
    __shared__ float tile[256][65];   // [o][n], 66.6 KB
    if (t < 64) {
        float m1 = Ml1[t], l1 = Ml1[64 + t];
        float m2 = Ml2[t], l2 = Ml2[64 + t];
        float m = fmaxf(m1, m2);
        float w1 = __expf(m1 - m) * l1;
        float w2 = __expf(m2 - m) * l2;
        float inv = 1.0f / (w1 + w2);
        c1s[t] = w1 * inv;
        c2s[t] = w2 * inv;
    }
    __syncthreads();
    int p2 = (t & 127) * 2;
    int nh = (t >> 7) * 32;
    float s0 = 0.f, s1 = 0.f, ss0 = 0.f, ss1 = 0.f;
    #pragma unroll 8
    for (int j = 0; j < 32; ++j) {
        int n = nh + j;
        f16x2 u1 = *(const f16x2*)&O1[n * 256 + p2];
        f16x2 u2 = *(const f16x2*)&O2[n * 256 + p2];
        float c1 = c1s[n], c2 = c2s[n];
        float v0 = c1 * (float)u1[0] + c2 * (float)u2[0];
        float v1 = c1 * (float)u1[1] + c2 * (float)u2[1];
        v0 = v0 >= 0.f ? v0 : 0.01f * v0;
        v1 = v1 >= 0.f ? v1 : 0.01f * v1;
        s0 += v0; ss0 += v0 * v0;
        s1 += v1; ss1 += v1 * v1;
        tile[p2][n] = v0;
        tile[p2 + 1][n] = v1;
    }
    atomicAdd(&stats[p2], s0);
    atomicAdd(&stats[p2 + 1], s1);
    atomicAdd(&stats[256 + p2], ss0);
    atomicAdd(&stats[257 + p2], ss1);
    __syncthreads();
    // coalesced store: wave w stores o-block [64w,64w+64), lanes = consecutive n
    int w = t >> 6, lane = t & 63;
    float* dst = out + (size_t)(b * OUT_) * N_ + n0;
    #pragma unroll
    for (int k = 0; k < 64; ++k) {
        int o = 64 * w + k;
        dst[(size_t)o * N_ + lane] = tile[o][lane];
    }
}

// ---------------------------------------------------------------------------
// Kernel E: y = gamma*(y-mean)*rstd + beta, finalizing mean/rstd from raw sums
// ---------------------------------------------------------------------------
__global__ __launch_bounds__(256) void k_bnapply(float* __restrict__ y,
                                                 const float* __restrict__ stats,
                                                 const float* __restrict__ gamma,
                                                 const float* __restrict__ beta) {
    int idx = blockIdx.x * 256 + threadIdx.x;
    int o = (idx >> 10) & 255;
    float mean = stats[o] * (1.0f / 16384.0f);
    float var = stats[256 + o] * (1.0f / 16384.0f) - mean * mean;
    float rstd = rsqrtf(var + 1e-5f);
    float g = gamma[o] * rstd;
    float bta = beta[o] - mean * g;
    float4 v = ((const float4*)y)[idx];
    v.x = v.x * g + bta;
    v.y = v.y * g + bta;
    v.z = v.z * g + bta;
    v.w = v.w * g + bta;
    ((float4*)y)[idx] = v;
}

extern "C" void kernel_launch(void* const* d_in, const int* in_sizes, int n_in,
                              void* d_out, int out_size, void* d_ws, size_t ws_size,
                              hipStream_t stream) {
    const float* x     = (const float*)d_in[0];
    const float* W     = (const float*)d_in[1];
    const float* gamma = (const float*)d_in[2];
    const float* beta  = (const float*)d_in[3];
    float* out = (float*)d_out;

    f16* xt    = (f16*)d_ws;                      // 8 MB
    f16* supT  = xt + (size_t)B_ * N_ * C_;       // 8 MB
    f16* Wt    = supT + (size_t)B_ * N_ * OUT_;   // 128 KB
    f16* Op    = Wt + C_ * OUT_;                  // 2*256*16384 f16 = 16 MB
    float* Ml  = (float*)(Op + (size_t)2 * 256 * 64 * 256);  // 256 KB
    float* stats = Ml + 512 * 128;                // 512 floats: sum, sumsq

    k_prep<<<1088, 256, 0, stream>>>(x, W, xt, Wt, stats);
    k_support<<<1024, 256, 0, stream>>>(xt, Wt, supT);
    k_flash<<<512, 256, 0, stream>>>(xt, supT, Op, Ml);
    k_merge<<<256, 256, 0, stream>>>(Op, Ml, out, stats);
    k_bnapply<<<4096, 256, 0, stream>>>(out, stats, gamma, beta);
}

// Round 2
// 234.682 us; speedup vs baseline: 1.3895x; 1.3895x over previous
//
#include <hip/hip_runtime.h>

typedef _Float16 f16;
typedef _Float16 f16x2 __attribute__((ext_vector_type(2)));
typedef _Float16 f16x8 __attribute__((ext_vector_type(8)));
typedef float f32x4 __attribute__((ext_vector_type(4)));

#define B_   4
#define C_   256
#define N_   4096
#define OUT_ 256

// async global->LDS, 16B per lane, dest = wave-uniform base + lane*16
__device__ __forceinline__ void gld_lds16(const f16* g, f16* l) {
    __builtin_amdgcn_global_load_lds(
        (const __attribute__((address_space(1))) void*)g,
        (__attribute__((address_space(3))) void*)l, 16, 0, 0);
}

// ---------------------------------------------------------------------------
// Kernel A: transpose+convert x [B,C,N] f32 -> xt [B,N,C] f16, W -> Wt[o][c] f16,
// and zero the 512-float stats accumulator (sum, sumsq per channel).
// ---------------------------------------------------------------------------
__global__ __launch_bounds__(256) void k_prep(const float* __restrict__ x,
                                              const float* __restrict__ W,
                                              f16* __restrict__ xt,
                                              f16* __restrict__ Wt,
                                              float* __restrict__ stats) {
    int bid = blockIdx.x;
    int t = threadIdx.x;
    if (bid < 1024) {
        int b  = bid >> 8;
        int ct = (bid >> 6) & 3;
        int nt = bid & 63;
        int c0 = ct * 64, n0 = nt * 64;
        __shared__ float tile[64][65];
        int nl = t & 63;
        int r0 = t >> 6;
        #pragma unroll
        for (int i = 0; i < 16; ++i) {
            int cl = i * 4 + r0;
            tile[cl][nl] = x[((b * C_ + c0 + cl) * N_) + n0 + nl];
        }
        __syncthreads();
        #pragma unroll
        for (int i = 0; i < 16; ++i) {
            int nl2 = i * 4 + r0;
            int cl2 = nl;
            xt[((b * N_ + n0 + nl2) * C_) + c0 + cl2] = (f16)tile[cl2][nl2];
        }
    } else {
        int wb = bid - 1024;
        #pragma unroll
        for (int i = 0; i < 4; ++i) {
            int idx = wb * 1024 + i * 256 + t;
            int c = idx >> 8, o = idx & 255;
            Wt[o * C_ + c] = (f16)W[idx];
        }
        if (wb < 2) stats[wb * 256 + t] = 0.f;
    }
}

// ---------------------------------------------------------------------------
// Kernel B: support^T[b][o][m] = sum_c xt[b][m][c] * W[c][o]   (f16 out)
// XCD-clustered bid remap: each XCD pair works on one batch (2.1 MB < 4 MB L2).
// ---------------------------------------------------------------------------
__global__ __launch_bounds__(256) void k_support(const f16* __restrict__ xt,
                                                 const f16* __restrict__ Wt,
                                                 f16* __restrict__ supT) {
    int bid0 = blockIdx.x;
    int bid = (bid0 & 7) * 128 + (bid0 >> 3);   // bijective, clusters b per XCD
    int b  = bid >> 8;
    int ot = (bid >> 6) & 3;
    int mt = bid & 63;
    int o0 = ot * 64, m0 = mt * 64;
    __shared__ __align__(16) f16 Ws[64][264];
    __shared__ __align__(16) f16 Xs[64][264];
    int t = threadIdx.x;
    int wave = t >> 6, lane = t & 63, q = lane >> 4, l15 = lane & 15;
    #pragma unroll
    for (int p = 0; p < 8; ++p) {
        int idx = p * 256 + t;
        int row = idx >> 5, ch = (idx & 31) * 8;
        *(uint4*)&Ws[row][ch] = *(const uint4*)&Wt[(o0 + row) * C_ + ch];
        *(uint4*)&Xs[row][ch] = *(const uint4*)&xt[((b * N_) + m0 + row) * C_ + ch];
    }
    __syncthreads();
    f32x4 acc[4] = {};
    #pragma unroll
    for (int kk = 0; kk < 8; ++kk) {
        f16x8 a = *(f16x8*)&Ws[16 * wave + l15][kk * 32 + q * 8];
        #pragma unroll
        for (int ct = 0; ct < 4; ++ct) {
            f16x8 bb = *(f16x8*)&Xs[16 * ct + l15][kk * 32 + q * 8];
            acc[ct] = __builtin_amdgcn_mfma_f32_16x16x32_f16(a, bb, acc[ct], 0, 0, 0);
        }
    }
    #pragma unroll
    for (int ct = 0; ct < 4; ++ct)
        #pragma unroll
        for (int r = 0; r < 4; ++r) {
            int og = o0 + 16 * wave + q * 4 + r;
            int mg = m0 + 16 * ct + l15;
            supT[((b * OUT_ + og) * N_) + mg] = (f16)acc[ct][r];
        }
}

// ---------------------------------------------------------------------------
// Kernel C: split-K flash. 512 blocks: (half h, batch b, n-tile nb), remapped
// so each XCD owns exactly one (h,b) pair (K-half 1MB + supT 2MB fits L2).
// K staging: global_load_lds (zero VGPR cost), single buffer, issued after
// barrier B (all Ks reads drained there), landed by barrier A's vmcnt(0).
// Ks is unpadded [64][256] with both-sides XOR swizzle (pre-swizzled global
// source + swizzled ds_read) for bank-conflict-free QK^T reads.
// V is read per-fragment straight from L2 (no LDS staging).
// amdgpu_waves_per_eu(2,2) pins occupancy -> allocator may use 256 VGPRs
// (round 1 spilled ~250 MB of scratch because it targeted ~100).
// ---------------------------------------------------------------------------
__global__ __launch_bounds__(256) __attribute__((amdgpu_waves_per_eu(2, 2)))
void k_flash(const f16* __restrict__ xt,
             const f16* __restrict__ supT,
             f16* __restrict__ Op,
             float* __restrict__ Ml) {
    int bid0 = blockIdx.x;
    int wg = (bid0 & 7) * 64 + (bid0 >> 3);   // XCD x owns wg in [64x, 64x+64)
    int h  = wg >> 8;
    int b  = (wg >> 6) & 3;
    int n0 = (wg & 63) * 64;

    __shared__ __align__(16) f16 KsL[64 * 256];  // 32768 B, swizzled content
    __shared__ __align__(16) f16 Ps[64][72];     //  9216 B
    __shared__ float Al[64];                     //   256 B  -> 42240 B total

    int t = threadIdx.x;
    int wave = t >> 6, lane = t & 63, q = lane >> 4, l15 = lane & 15;

    // Q fragments in registers
    const f16* qbase = xt + ((size_t)(b * N_) + n0 + 16 * wave + l15) * C_;
    f16x8 qf[8];
    #pragma unroll
    for (int kk = 0; kk < 8; ++kk)
        qf[kk] = *(const f16x8*)&qbase[kk * 32 + q * 8];

    f32x4 oacc[4][4] = {};
    float m_run[4], l_run[4];
    #pragma unroll
    for (int r = 0; r < 4; ++r) { m_run[r] = -1e30f; l_run[r] = 0.f; }

    // K staging source offsets (f16 units), pre-swizzled so linear LDS dest
    // yields swizzled content: LDS[row*256 + c] = G[row*256 + (c ^ swz(row))].
    // Wave w, call j covers LDS chunk [w*4096 + j*512, +512) f16
    //   -> row = w*16 + 2j + (lane>>5), col16 = (lane&31)*8.
    const f16* kbase = xt + (size_t)b * N_ * C_;
    int c16 = (lane & 31) * 8;
    int rhalf = lane >> 5;
    int soff[8];
    #pragma unroll
    for (int j = 0; j < 8; ++j) {
        int row = wave * 16 + j * 2 + rhalf;
        soff[j] = row * 256 + (c16 ^ ((row & 7) << 3));
    }
    int swr = (l15 & 7) << 3;   // read-side swizzle (f16 units)

    // prologue: stage K tile 0
    {
        const f16* kt = kbase + (size_t)(h * 2048) * C_;
        #pragma unroll
        for (int j = 0; j < 8; ++j)
            gld_lds16(kt + soff[j], &KsL[wave * 4096 + j * 512]);
    }

    for (int it = 0; it < 32; ++it) {
        int m0 = h * 2048 + it * 64;

        // A: K tile landed (own loads drained, then all waves synced)
        asm volatile("s_waitcnt vmcnt(0) lgkmcnt(0)" ::: "memory");
        __builtin_amdgcn_s_barrier();
        __builtin_amdgcn_sched_barrier(0);

        // S = Q K^T (64x64, K=256); wave owns rows 16*wave..+15
        f32x4 sacc[4] = {};
        __builtin_amdgcn_s_setprio(1);
        #pragma unroll
        for (int kk = 0; kk < 8; ++kk) {
            int col = (kk * 32 + q * 8) ^ swr;
            #pragma unroll
            for (int ct = 0; ct < 4; ++ct) {
                f16x8 bb = *(f16x8*)&KsL[(16 * ct + l15) * 256 + col];
                sacc[ct] = __builtin_amdgcn_mfma_f32_16x16x32_f16(qf[kk], bb, sacc[ct], 0, 0, 0);
            }
        }
        __builtin_amdgcn_s_setprio(0);

        // V fragments for THIS iter straight from global (L2-resident);
        // latency hides under softmax + barrier
        f16x8 vf[2][4];
        const f16* vb = supT + ((size_t)(b * OUT_) + 64 * wave + l15) * N_ + m0 + q * 8;
        #pragma unroll
        for (int ks = 0; ks < 2; ++ks)
            #pragma unroll
            for (int ot = 0; ot < 4; ++ot)
                vf[ks][ot] = *(const f16x8*)&vb[(size_t)(16 * ot) * N_ + ks * 32];

        // online softmax on own rows; publish P (f16) and alpha
        float alpha[4];
        #pragma unroll
        for (int r = 0; r < 4; ++r) {
            float mx = fmaxf(fmaxf(sacc[0][r], sacc[1][r]), fmaxf(sacc[2][r], sacc[3][r]));
            mx = fmaxf(mx, __shfl_xor(mx, 1));
            mx = fmaxf(mx, __shfl_xor(mx, 2));
            mx = fmaxf(mx, __shfl_xor(mx, 4));
            mx = fmaxf(mx, __shfl_xor(mx, 8));
            float mnew = fmaxf(m_run[r], mx);
            alpha[r] = __expf(m_run[r] - mnew);
            m_run[r] = mnew;
            float p0 = __expf(sacc[0][r] - mnew);
            float p1 = __expf(sacc[1][r] - mnew);
            float p2 = __expf(sacc[2][r] - mnew);
            float p3 = __expf(sacc[3][r] - mnew);
            float sum = p0 + p1 + p2 + p3;
            sum += __shfl_xor(sum, 1);
            sum += __shfl_xor(sum, 2);
            sum += __shfl_xor(sum, 4);
            sum += __shfl_xor(sum, 8);
            l_run[r] = l_run[r] * alpha[r] + sum;
            int row = 16 * wave + q * 4 + r;
            Ps[row][0 * 16 + l15] = (f16)p0;
            Ps[row][1 * 16 + l15] = (f16)p1;
            Ps[row][2 * 16 + l15] = (f16)p2;
            Ps[row][3 * 16 + l15] = (f16)p3;
            if (l15 == 0) Al[row] = alpha[r];
        }

        // B: light barrier — drain LDS only; vf global loads stay in flight
        asm volatile("s_waitcnt lgkmcnt(0)" ::: "memory");
        __builtin_amdgcn_s_barrier();
        __builtin_amdgcn_sched_barrier(0);

        // stage NEXT K tile (safe: all Ks reads chip-wide drained at B);
        // stays in flight under rescale+PV, landed at next barrier A
        if (it < 31) {
            const f16* kt = kbase + (size_t)(m0 + 64) * C_;
            #pragma unroll
            for (int j = 0; j < 8; ++j)
                gld_lds16(kt + soff[j], &KsL[wave * 4096 + j * 512]);
        }

        // rescale O by alpha (broadcast via LDS), then O += P V
        float4 av[4];
        #pragma unroll
        for (int nt = 0; nt < 4; ++nt)
            av[nt] = *(const float4*)&Al[16 * nt + 4 * q];
        #pragma unroll
        for (int nt = 0; nt < 4; ++nt)
            #pragma unroll
            for (int ot = 0; ot < 4; ++ot)
                #pragma unroll
                for (int r = 0; r < 4; ++r)
                    oacc[nt][ot][r] *= ((const float*)&av[nt])[r];

        __builtin_amdgcn_s_setprio(1);
        #pragma unroll
        for (int ks = 0; ks < 2; ++ks) {
            f16x8 af[4];
            #pragma unroll
            for (int nt = 0; nt < 4; ++nt)
                af[nt] = *(f16x8*)&Ps[16 * nt + l15][ks * 32 + q * 8];
            #pragma unroll
            for (int nt = 0; nt < 4; ++nt)
                #pragma unroll
                for (int ot = 0; ot < 4; ++ot)
                    oacc[nt][ot] = __builtin_amdgcn_mfma_f32_16x16x32_f16(af[nt], vf[ks][ot], oacc[nt][ot], 0, 0, 0);
        }
        __builtin_amdgcn_s_setprio(0);
    }

    __syncthreads();   // all waves done with last rescale's Al reads
    if (l15 == 0) {
        #pragma unroll
        for (int r = 0; r < 4; ++r)
            Al[16 * wave + q * 4 + r] = 1.0f / l_run[r];
    }
    __syncthreads();
    float4 lv[4];
    #pragma unroll
    for (int nt = 0; nt < 4; ++nt)
        lv[nt] = *(const float4*)&Al[16 * nt + 4 * q];

    f16* Obase = Op + (size_t)wg * (64 * 256);
    #pragma unroll
    for (int nt = 0; nt < 4; ++nt)
        #pragma unroll
        for (int ot = 0; ot < 4; ++ot)
            #pragma unroll
            for (int r = 0; r < 4; ++r) {
                int n = 16 * nt + q * 4 + r;
                int o = 64 * wave + 16 * ot + l15;
                Obase[n * 256 + o] = (f16)(oacc[nt][ot][r] * ((const float*)&lv[nt])[r]);
            }
    float* Mlb = Ml + (size_t)wg * 128;
    if (l15 == 0) {
        #pragma unroll
        for (int r = 0; r < 4; ++r) {
            Mlb[16 * wave + q * 4 + r] = m_run[r];
            Mlb[64 + 16 * wave + q * 4 + r] = l_run[r];
        }
    }
}

// ---------------------------------------------------------------------------
// Kernel C2: merge the two split-K halves + LeakyReLU + fused BN partial sums
// + coalesced transpose store via LDS. grid 256 = (b, nb).
// ---------------------------------------------------------------------------
__global__ __launch_bounds__(256) void k_merge(const f16* __restrict__ Op,
                                               const float* __restrict__ Ml,
                                               float* __restrict__ out,
                                               float* __restrict__ stats) {
    int bid = blockIdx.x;
    int b  = bid >> 6;
    int n0 = (bid & 63) * 64;
    int t = threadIdx.x;
    const f16* O1 = Op + (size_t)bid * (64 * 256);
    const f16* O2 = Op + (size_t)(bid + 256) * (64 * 256);
    const float* Ml1 = Ml + (size_t)bid * 128;
    const float* Ml2 = Ml + (size_t)(bid + 256) * 128;
    __shared__ float c1s[64], c2s[64];
    __shared__ float tile[256][65];   // [o][n], 66.6 KB
    if (t < 64) {
        float m1 = Ml1[t], l1 = Ml1[64 + t];
        float m2 = Ml2[t], l2 = Ml2[64 + t];
        float m = fmaxf(m1, m2);
        float w1 = __expf(m1 - m) * l1;
        float w2 = __expf(m2 - m) * l2;
        float inv = 1.0f / (w1 + w2);
        c1s[t] = w1 * inv;
        c2s[t] = w2 * inv;
    }
    __syncthreads();
    int p2 = (t & 127) * 2;
    int nh = (t >> 7) * 32;
    float s0 = 0.f, s1 = 0.f, ss0 = 0.f, ss1 = 0.f;
    #pragma unroll 8
    for (int j = 0; j < 32; ++j) {
        int n = nh + j;
        f16x2 u1 = *(const f16x2*)&O1[n * 256 + p2];
        f16x2 u2 = *(const f16x2*)&O2[n * 256 + p2];
        float c1 = c1s[n], c2 = c2s[n];
        float v0 = c1 * (float)u1[0] + c2 * (float)u2[0];
        float v1 = c1 * (float)u1[1] + c2 * (float)u2[1];
        v0 = v0 >= 0.f ? v0 : 0.01f * v0;
        v1 = v1 >= 0.f ? v1 : 0.01f * v1;
        s0 += v0; ss0 += v0 * v0;
        s1 += v1; ss1 += v1 * v1;
        tile[p2][n] = v0;
        tile[p2 + 1][n] = v1;
    }
    atomicAdd(&stats[p2], s0);
    atomicAdd(&stats[p2 + 1], s1);
    atomicAdd(&stats[256 + p2], ss0);
    atomicAdd(&stats[257 + p2], ss1);
    __syncthreads();
    // coalesced store: wave w stores o-block [64w,64w+64), lanes = consecutive n
    int w = t >> 6, lane = t & 63;
    float* dst = out + (size_t)(b * OUT_) * N_ + n0;
    #pragma unroll
    for (int k = 0; k < 64; ++k) {
        int o = 64 * w + k;
        dst[(size_t)o * N_ + lane] = tile[o][lane];
    }
}

// ---------------------------------------------------------------------------
// Kernel E: y = gamma*(y-mean)*rstd + beta, finalizing mean/rstd from raw sums
// ---------------------------------------------------------------------------
__global__ __launch_bounds__(256) void k_bnapply(float* __restrict__ y,
                                                 const float* __restrict__ stats,
                                                 const float* __restrict__ gamma,
                                                 const float* __restrict__ beta) {
    int idx = blockIdx.x * 256 + threadIdx.x;
    int o = (idx >> 10) & 255;
    float mean = stats[o] * (1.0f / 16384.0f);
    float var = stats[256 + o] * (1.0f / 16384.0f) - mean * mean;
    float rstd = rsqrtf(var + 1e-5f);
    float g = gamma[o] * rstd;
    float bta = beta[o] - mean * g;
    float4 v = ((const float4*)y)[idx];
    v.x = v.x * g + bta;
    v.y = v.y * g + bta;
    v.z = v.z * g + bta;
    v.w = v.w * g + bta;
    ((float4*)y)[idx] = v;
}

extern "C" void kernel_launch(void* const* d_in, const int* in_sizes, int n_in,
                              void* d_out, int out_size, void* d_ws, size_t ws_size,
                              hipStream_t stream) {
    const float* x     = (const float*)d_in[0];
    const float* W     = (const float*)d_in[1];
    const float* gamma = (const float*)d_in[2];
    const float* beta  = (const float*)d_in[3];
    float* out = (float*)d_out;

    f16* xt    = (f16*)d_ws;                      // 8 MB
    f16* supT  = xt + (size_t)B_ * N_ * C_;       // 8 MB
    f16* Wt    = supT + (size_t)B_ * N_ * OUT_;   // 128 KB
    f16* Op    = Wt + C_ * OUT_;                  // 2*256*16384 f16 = 16 MB
    float* Ml  = (float*)(Op + (size_t)2 * 256 * 64 * 256);  // 256 KB
    float* stats = Ml + 512 * 128;                // 512 floats: sum, sumsq

    k_prep<<<1088, 256, 0, stream>>>(x, W, xt, Wt, stats);
    k_support<<<1024, 256, 0, stream>>>(xt, Wt, supT);
    k_flash<<<512, 256, 0, stream>>>(xt, supT, Op, Ml);
    k_merge<<<256, 256, 0, stream>>>(Op, Ml, out, stats);
    k_bnapply<<<4096, 256, 0, stream>>>(out, stats, gamma, beta);
}

// Round 3
// 214.535 us; speedup vs baseline: 1.5200x; 1.0939x over previous
//
#include <hip/hip_runtime.h>

typedef _Float16 f16;
typedef _Float16 f16x2 __attribute__((ext_vector_type(2)));
typedef _Float16 f16x8 __attribute__((ext_vector_type(8)));
typedef float f32x4 __attribute__((ext_vector_type(4)));

#define B_   4
#define C_   256
#define N_   4096
#define OUT_ 256

// async global->LDS, 16B per lane, dest = wave-uniform base + lane*16
__device__ __forceinline__ void gld_lds16(const f16* g, f16* l) {
    __builtin_amdgcn_global_load_lds(
        (const __attribute__((address_space(1))) void*)g,
        (__attribute__((address_space(3))) void*)l, 16, 0, 0);
}

// ---------------------------------------------------------------------------
// Kernel A: transpose+convert x [B,C,N] f32 -> xt [B,N,C] f16, W -> Wt[o][c] f16,
// and zero the 512-float stats accumulator (sum, sumsq per channel).
// ---------------------------------------------------------------------------
__global__ __launch_bounds__(256) void k_prep(const float* __restrict__ x,
                                              const float* __restrict__ W,
                                              f16* __restrict__ xt,
                                              f16* __restrict__ Wt,
                                              float* __restrict__ stats) {
    int bid = blockIdx.x;
    int t = threadIdx.x;
    if (bid < 1024) {
        int b  = bid >> 8;
        int ct = (bid >> 6) & 3;
        int nt = bid & 63;
        int c0 = ct * 64, n0 = nt * 64;
        __shared__ float tile[64][65];
        int nl = t & 63;
        int r0 = t >> 6;
        #pragma unroll
        for (int i = 0; i < 16; ++i) {
            int cl = i * 4 + r0;
            tile[cl][nl] = x[((b * C_ + c0 + cl) * N_) + n0 + nl];
        }
        __syncthreads();
        #pragma unroll
        for (int i = 0; i < 16; ++i) {
            int nl2 = i * 4 + r0;
            int cl2 = nl;
            xt[((b * N_ + n0 + nl2) * C_) + c0 + cl2] = (f16)tile[cl2][nl2];
        }
    } else {
        int wb = bid - 1024;
        #pragma unroll
        for (int i = 0; i < 4; ++i) {
            int idx = wb * 1024 + i * 256 + t;
            int c = idx >> 8, o = idx & 255;
            Wt[o * C_ + c] = (f16)W[idx];
        }
        if (wb < 2) stats[wb * 256 + t] = 0.f;
    }
}

// ---------------------------------------------------------------------------
// Kernel B: support^T[b][o][m] = sum_c xt[b][m][c] * W[c][o]   (f16 out)
// ---------------------------------------------------------------------------
__global__ __launch_bounds__(256) void k_support(const f16* __restrict__ xt,
                                                 const f16* __restrict__ Wt,
                                                 f16* __restrict__ supT) {
    int bid0 = blockIdx.x;
    int bid = (bid0 & 7) * 128 + (bid0 >> 3);   // bijective, clusters b per XCD
    int b  = bid >> 8;
    int ot = (bid >> 6) & 3;
    int mt = bid & 63;
    int o0 = ot * 64, m0 = mt * 64;
    __shared__ __align__(16) f16 Ws[64][264];
    __shared__ __align__(16) f16 Xs[64][264];
    int t = threadIdx.x;
    int wave = t >> 6, lane = t & 63, q = lane >> 4, l15 = lane & 15;
    #pragma unroll
    for (int p = 0; p < 8; ++p) {
        int idx = p * 256 + t;
        int row = idx >> 5, ch = (idx & 31) * 8;
        *(uint4*)&Ws[row][ch] = *(const uint4*)&Wt[(o0 + row) * C_ + ch];
        *(uint4*)&Xs[row][ch] = *(const uint4*)&xt[((b * N_) + m0 + row) * C_ + ch];
    }
    __syncthreads();
    f32x4 acc[4] = {};
    #pragma unroll
    for (int kk = 0; kk < 8; ++kk) {
        f16x8 a = *(f16x8*)&Ws[16 * wave + l15][kk * 32 + q * 8];
        #pragma unroll
        for (int ct = 0; ct < 4; ++ct) {
            f16x8 bb = *(f16x8*)&Xs[16 * ct + l15][kk * 32 + q * 8];
            acc[ct] = __builtin_amdgcn_mfma_f32_16x16x32_f16(a, bb, acc[ct], 0, 0, 0);
        }
    }
    #pragma unroll
    for (int ct = 0; ct < 4; ++ct)
        #pragma unroll
        for (int r = 0; r < 4; ++r) {
            int og = o0 + 16 * wave + q * 4 + r;
            int mg = m0 + 16 * ct + l15;
            supT[((b * OUT_ + og) * N_) + mg] = (f16)acc[ct][r];
        }
}

// ---------------------------------------------------------------------------
// Kernel C: split-K flash, swapped-QK^T register-local softmax.
// sacc[mt] = mfma(K_frag, Q_frag): D[m][n], m = 16mt+4q+r (regs+quads),
// n = l15 (per-lane). Softmax over m = 15-op register tree + shfl_xor(16,32)
// (was 32 shfls/iter). m_run/l_run are scalars per lane (n = 16w+l15).
// Ks double-buffered via global_load_lds; V frags + next-K issued at iter top
// (vf first so PV's wait keeps K loads in flight) -> no VMEM stalls.
// Ps content/PV unchanged from round 2.
// LDS: 2*32KB Ks + 9KB Ps + Al = 75 KB -> 2 blocks/CU.
// ---------------------------------------------------------------------------
__global__ __launch_bounds__(256) __attribute__((amdgpu_waves_per_eu(2, 2)))
void k_flash(const f16* __restrict__ xt,
             const f16* __restrict__ supT,
             f16* __restrict__ Op,
             float* __restrict__ Ml) {
    int bid0 = blockIdx.x;
    int wg = (bid0 & 7) * 64 + (bid0 >> 3);   // XCD x owns wg in [64x, 64x+64)
    int h  = wg >> 8;
    int b  = (wg >> 6) & 3;
    int n0 = (wg & 63) * 64;

    __shared__ __align__(16) f16 KsL[2][64 * 256];  // 65536 B, swizzled content
    __shared__ __align__(16) f16 Ps[64][72];        //  9216 B
    __shared__ float Al[64];                        //   256 B  -> 75008 B total

    int t = threadIdx.x;
    int wave = t >> 6, lane = t & 63, q = lane >> 4, l15 = lane & 15;

    // Q fragments in registers (B-operand: row = l15, k-chunk = q*8)
    const f16* qbase = xt + ((size_t)(b * N_) + n0 + 16 * wave + l15) * C_;
    f16x8 qf[8];
    #pragma unroll
    for (int kk = 0; kk < 8; ++kk)
        qf[kk] = *(const f16x8*)&qbase[kk * 32 + q * 8];

    f32x4 oacc[4][4] = {};
    float m_run = -1e30f, l_run = 0.f;   // for n = n0 + 16*wave + l15

    // K staging source offsets (f16 units), pre-swizzled so linear LDS dest
    // yields swizzled content: LDS[row*256 + c] = G[row*256 + (c ^ swz(row))].
    const f16* kbase = xt + (size_t)b * N_ * C_;
    int c16 = (lane & 31) * 8;
    int rhalf = lane >> 5;
    int soff[8];
    #pragma unroll
    for (int j = 0; j < 8; ++j) {
        int row = wave * 16 + j * 2 + rhalf;
        soff[j] = row * 256 + (c16 ^ ((row & 7) << 3));
    }
    int swr = (l15 & 7) << 3;   // read-side swizzle (f16 units)

    // prologue: stage K tile 0 into buffer 0
    {
        const f16* kt = kbase + (size_t)(h * 2048) * C_;
        #pragma unroll
        for (int j = 0; j < 8; ++j)
            gld_lds16(kt + soff[j], &KsL[0][wave * 4096 + j * 512]);
    }

    int cur = 0;
    for (int it = 0; it < 32; ++it) {
        int m0 = h * 2048 + it * 64;

        // A: K[it] landed in KsL[cur] (vmcnt(0) inside), all waves synced
        __syncthreads();

        // V fragments for THIS iter (consumed in PV; issued first so the PV
        // wait leaves the younger K-loads in flight)
        f16x8 vf[2][4];
        const f16* vb = supT + ((size_t)(b * OUT_) + 64 * wave + l15) * N_ + m0 + q * 8;
        #pragma unroll
        for (int ks = 0; ks < 2; ++ks)
            #pragma unroll
            for (int ot = 0; ot < 4; ++ot)
                vf[ks][ot] = *(const f16x8*)&vb[(size_t)(16 * ot) * N_ + ks * 32];

        // stage NEXT K tile into the other buffer (full iteration of slack)
        if (it < 31) {
            const f16* kt = kbase + (size_t)(m0 + 64) * C_;
            #pragma unroll
            for (int j = 0; j < 8; ++j)
                gld_lds16(kt + soff[j], &KsL[cur ^ 1][wave * 4096 + j * 512]);
        }

        // S^T = K Q^T (64 m x 16 n per wave, K=256): sacc[mt][r] =
        // S[m = 16mt+4q+r][n = 16w+l15]
        f32x4 sacc[4] = {};
        __builtin_amdgcn_s_setprio(1);
        #pragma unroll
        for (int kk = 0; kk < 8; ++kk) {
            int col = (kk * 32 + q * 8) ^ swr;
            #pragma unroll
            for (int mt = 0; mt < 4; ++mt) {
                f16x8 kf = *(f16x8*)&KsL[cur][(16 * mt + l15) * 256 + col];
                sacc[mt] = __builtin_amdgcn_mfma_f32_16x16x32_f16(kf, qf[kk], sacc[mt], 0, 0, 0);
            }
        }
        __builtin_amdgcn_s_setprio(0);

        // register-local softmax over m: 15-op tree + 2 shfls
        float mt0 = fmaxf(fmaxf(sacc[0][0], sacc[0][1]), fmaxf(sacc[0][2], sacc[0][3]));
        float mt1 = fmaxf(fmaxf(sacc[1][0], sacc[1][1]), fmaxf(sacc[1][2], sacc[1][3]));
        float mt2 = fmaxf(fmaxf(sacc[2][0], sacc[2][1]), fmaxf(sacc[2][2], sacc[2][3]));
        float mt3 = fmaxf(fmaxf(sacc[3][0], sacc[3][1]), fmaxf(sacc[3][2], sacc[3][3]));
        float mx = fmaxf(fmaxf(mt0, mt1), fmaxf(mt2, mt3));
        mx = fmaxf(mx, __shfl_xor(mx, 16));
        mx = fmaxf(mx, __shfl_xor(mx, 32));
        float mnew = fmaxf(m_run, mx);
        float alpha = __expf(m_run - mnew);
        m_run = mnew;

        float p[4][4];
        #pragma unroll
        for (int mt = 0; mt < 4; ++mt)
            #pragma unroll
            for (int r = 0; r < 4; ++r)
                p[mt][r] = __expf(sacc[mt][r] - mnew);
        float s0 = (p[0][0] + p[0][1]) + (p[0][2] + p[0][3]);
        float s1 = (p[1][0] + p[1][1]) + (p[1][2] + p[1][3]);
        float s2 = (p[2][0] + p[2][1]) + (p[2][2] + p[2][3]);
        float s3 = (p[3][0] + p[3][1]) + (p[3][2] + p[3][3]);
        float sum = (s0 + s1) + (s2 + s3);
        sum += __shfl_xor(sum, 16);
        sum += __shfl_xor(sum, 32);
        l_run = l_run * alpha + sum;

        // publish P: Ps[n = 16w+l15][m = 16mt+4q + 2j..] as packed f16x2
        #pragma unroll
        for (int mt = 0; mt < 4; ++mt)
            #pragma unroll
            for (int j = 0; j < 2; ++j) {
                f16x2 pp = { (f16)p[mt][2 * j], (f16)p[mt][2 * j + 1] };
                *(f16x2*)&Ps[16 * wave + l15][16 * mt + 4 * q + 2 * j] = pp;
            }
        if (lane < 16) Al[16 * wave + lane] = alpha;

        // B: light barrier — drain LDS only; vf/K global loads stay in flight
        asm volatile("s_waitcnt lgkmcnt(0)" ::: "memory");
        __builtin_amdgcn_s_barrier();
        __builtin_amdgcn_sched_barrier(0);

        // rescale O by alpha (broadcast via LDS), then O += P V
        float4 av[4];
        #pragma unroll
        for (int nt = 0; nt < 4; ++nt)
            av[nt] = *(const float4*)&Al[16 * nt + 4 * q];
        #pragma unroll
        for (int nt = 0; nt < 4; ++nt)
            #pragma unroll
            for (int ot = 0; ot < 4; ++ot)
                #pragma unroll
                for (int r = 0; r < 4; ++r)
                    oacc[nt][ot][r] *= ((const float*)&av[nt])[r];

        __builtin_amdgcn_s_setprio(1);
        #pragma unroll
        for (int ks = 0; ks < 2; ++ks) {
            f16x8 af[4];
            #pragma unroll
            for (int nt = 0; nt < 4; ++nt)
                af[nt] = *(f16x8*)&Ps[16 * nt + l15][ks * 32 + q * 8];
            #pragma unroll
            for (int nt = 0; nt < 4; ++nt)
                #pragma unroll
                for (int ot = 0; ot < 4; ++ot)
                    oacc[nt][ot] = __builtin_amdgcn_mfma_f32_16x16x32_f16(af[nt], vf[ks][ot], oacc[nt][ot], 0, 0, 0);
        }
        __builtin_amdgcn_s_setprio(0);
        cur ^= 1;
    }

    __syncthreads();   // all waves done with last rescale's Al reads
    if (lane < 16) Al[16 * wave + lane] = 1.0f / l_run;
    __syncthreads();
    float4 lv[4];
    #pragma unroll
    for (int nt = 0; nt < 4; ++nt)
        lv[nt] = *(const float4*)&Al[16 * nt + 4 * q];

    f16* Obase = Op + (size_t)wg * (64 * 256);
    #pragma unroll
    for (int nt = 0; nt < 4; ++nt)
        #pragma unroll
        for (int ot = 0; ot < 4; ++ot)
            #pragma unroll
            for (int r = 0; r < 4; ++r) {
                int n = 16 * nt + q * 4 + r;
                int o = 64 * wave + 16 * ot + l15;
                Obase[n * 256 + o] = (f16)(oacc[nt][ot][r] * ((const float*)&lv[nt])[r]);
            }
    float* Mlb = Ml + (size_t)wg * 128;
    if (lane < 16) {
        Mlb[16 * wave + lane] = m_run;
        Mlb[64 + 16 * wave + lane] = l_run;
    }
}

// ---------------------------------------------------------------------------
// Kernel C2: merge the two split-K halves + LeakyReLU + fused BN partial sums
// + coalesced transpose store via LDS. grid 256 = (b, nb).
// ---------------------------------------------------------------------------
__global__ __launch_bounds__(256) void k_merge(const f16* __restrict__ Op,
                                               const float* __restrict__ Ml,
                                               float* __restrict__ out,
                                               float* __restrict__ stats) {
    int bid = blockIdx.x;
    int b  = bid >> 6;
    int n0 = (bid & 63) * 64;
    int t = threadIdx.x;
    const f16* O1 = Op + (size_t)bid * (64 * 256);
    const f16* O2 = Op + (size_t)(bid + 256) * (64 * 256);
    const float* Ml1 = Ml + (size_t)bid * 128;
    const float* Ml2 = Ml + (size_t)(bid + 256) * 128;
    __shared__ float c1s[64], c2s[64];
    __shared__ float tile[256][65];   // [o][n], 66.6 KB
    if (t < 64) {
        float m1 = Ml1[t], l1 = Ml1[64 + t];
        float m2 = Ml2[t], l2 = Ml2[64 + t];
        float m = fmaxf(m1, m2);
        float w1 = __expf(m1 - m) * l1;
        float w2 = __expf(m2 - m) * l2;
        float inv = 1.0f / (w1 + w2);
        c1s[t] = w1 * inv;
        c2s[t] = w2 * inv;
    }
    __syncthreads();
    int p2 = (t & 127) * 2;
    int nh = (t >> 7) * 32;
    float s0 = 0.f, s1 = 0.f, ss0 = 0.f, ss1 = 0.f;
    #pragma unroll 8
    for (int j = 0; j < 32; ++j) {
        int n = nh + j;
        f16x2 u1 = *(const f16x2*)&O1[n * 256 + p2];
        f16x2 u2 = *(const f16x2*)&O2[n * 256 + p2];
        float c1 = c1s[n], c2 = c2s[n];
        float v0 = c1 * (float)u1[0] + c2 * (float)u2[0];
        float v1 = c1 * (float)u1[1] + c2 * (float)u2[1];
        v0 = v0 >= 0.f ? v0 : 0.01f * v0;
        v1 = v1 >= 0.f ? v1 : 0.01f * v1;
        s0 += v0; ss0 += v0 * v0;
        s1 += v1; ss1 += v1 * v1;
        tile[p2][n] = v0;
        tile[p2 + 1][n] = v1;
    }
    atomicAdd(&stats[p2], s0);
    atomicAdd(&stats[p2 + 1], s1);
    atomicAdd(&stats[256 + p2], ss0);
    atomicAdd(&stats[257 + p2], ss1);
    __syncthreads();
    // coalesced store: wave w stores o-block [64w,64w+64), lanes = consecutive n
    int w = t >> 6, lane = t & 63;
    float* dst = out + (size_t)(b * OUT_) * N_ + n0;
    #pragma unroll
    for (int k = 0; k < 64; ++k) {
        int o = 64 * w + k;
        dst[(size_t)o * N_ + lane] = tile[o][lane];
    }
}

// ---------------------------------------------------------------------------
// Kernel E: y = gamma*(y-mean)*rstd + beta, finalizing mean/rstd from raw sums
// ---------------------------------------------------------------------------
__global__ __launch_bounds__(256) void k_bnapply(float* __restrict__ y,
                                                 const float* __restrict__ stats,
                                                 const float* __restrict__ gamma,
                                                 const float* __restrict__ beta) {
    int idx = blockIdx.x * 256 + threadIdx.x;
    int o = (idx >> 10) & 255;
    float mean = stats[o] * (1.0f / 16384.0f);
    float var = stats[256 + o] * (1.0f / 16384.0f) - mean * mean;
    float rstd = rsqrtf(var + 1e-5f);
    float g = gamma[o] * rstd;
    float bta = beta[o] - mean * g;
    float4 v = ((const float4*)y)[idx];
    v.x = v.x * g + bta;
    v.y = v.y * g + bta;
    v.z = v.z * g + bta;
    v.w = v.w * g + bta;
    ((float4*)y)[idx] = v;
}

extern "C" void kernel_launch(void* const* d_in, const int* in_sizes, int n_in,
                              void* d_out, int out_size, void* d_ws, size_t ws_size,
                              hipStream_t stream) {
    const float* x     = (const float*)d_in[0];
    const float* W     = (const float*)d_in[1];
    const float* gamma = (const float*)d_in[2];
    const float* beta  = (const float*)d_in[3];
    float* out = (float*)d_out;

    f16* xt    = (f16*)d_ws;                      // 8 MB
    f16* supT  = xt + (size_t)B_ * N_ * C_;       // 8 MB
    f16* Wt    = supT + (size_t)B_ * N_ * OUT_;   // 128 KB
    f16* Op    = Wt + C_ * OUT_;                  // 2*256*16384 f16 = 16 MB
    float* Ml  = (float*)(Op + (size_t)2 * 256 * 64 * 256);  // 256 KB
    float* stats = Ml + 512 * 128;                // 512 floats: sum, sumsq

    k_prep<<<1088, 256, 0, stream>>>(x, W, xt, Wt, stats);
    k_support<<<1024, 256, 0, stream>>>(xt, Wt, supT);
    k_flash<<<512, 256, 0, stream>>>(xt, supT, Op, Ml);
    k_merge<<<256, 256, 0, stream>>>(Op, Ml, out, stats);
    k_bnapply<<<4096, 256, 0, stream>>>(out, stats, gamma, beta);
}